// Round 1
// baseline (218.980 us; speedup 1.0000x reference)
//
#include <hip/hip_runtime.h>
#include <stdint.h>

// MultiHeadCrossAttention: B=2, SQ=SK=2048, D=1024, H=16, Dh=64, scale=1/8.
// fp32 in/out, bf16 MFMA internal.
// R11: gemm_core was the m97 2-barrier structure (stage -> drain -> compute fully
//      serialized per K-step): counters showed everything idle (Mfma 14.7%, VALU 19%,
//      HBM 12%, occ ~16%) => latency-bound. Replaced with single-barrier double-
//      buffered pipeline: issue tile kt+1's global_load_lds BEFORE compute of kt;
//      one __syncthreads per K-step drains both (compiler emits vmcnt(0)+lgkmcnt(0)
//      before s_barrier => provably race-free, no raw barriers, no counted vmcnt).
//      LDS: gemm_qkv 32->64 KB (2 blocks/CU), gemm_out 24->48 KB. Attn unchanged.

typedef unsigned short u16b;
typedef __attribute__((ext_vector_type(4))) short short4v;
typedef __attribute__((ext_vector_type(8))) short short8v;
typedef __attribute__((ext_vector_type(4))) float float4v;
typedef __attribute__((ext_vector_type(2))) unsigned int uint2v;

#if __has_builtin(__builtin_amdgcn_exp2f)
__device__ __forceinline__ float exp2_fast(float x){ return __builtin_amdgcn_exp2f(x); }
#else
__device__ __forceinline__ float exp2_fast(float x){ return exp2f(x); }
#endif

__device__ __forceinline__ u16b f2bf(float f) {
  union { float f; unsigned int i; } v; v.f = f;
  return (u16b)((v.i + 0x7fffu + ((v.i >> 16) & 1u)) >> 16);  // RNE
}
__device__ __forceinline__ void gl_lds16(const u16b* g, u16b* l) {
  __builtin_amdgcn_global_load_lds(
      (const __attribute__((address_space(1))) void*)g,
      (__attribute__((address_space(3))) void*)l, 16, 0, 0);
}

// ---------------- prep: y=0,1 -> cvt x1/x2 fp32->bf16 ; y=2..5 -> transpose W[y-2] ---
__global__ __launch_bounds__(256) void prep(
    const float* __restrict__ x1, const float* __restrict__ x2,
    const float* __restrict__ W0, const float* __restrict__ W1,
    const float* __restrict__ W2, const float* __restrict__ W3,
    u16b* __restrict__ x1b, u16b* __restrict__ x2b, u16b* __restrict__ WT) {
  const int tid = threadIdx.x;
  const int mode = blockIdx.y;
  if (mode < 2) {
    const float* src = mode ? x2 : x1;
    u16b* dst = mode ? x2b : x1b;
    const int n4 = 1024*1024;             // 4Mi elems / 4
    int i = blockIdx.x * 256 + tid;
    const int stride = gridDim.x * 256;
    for (; i < n4; i += stride) {
      float4v v = ((const float4v*)src)[i];
      short4v o;
      o[0]=(short)f2bf(v[0]); o[1]=(short)f2bf(v[1]);
      o[2]=(short)f2bf(v[2]); o[3]=(short)f2bf(v[3]);
      ((short4v*)dst)[i] = o;
    }
  } else {
    __shared__ u16b tile[32][33];
    const int z = mode - 2;
    const float* src = (z==0) ? W0 : (z==1) ? W1 : (z==2) ? W2 : W3;
    u16b* dst = WT + (size_t)z * (1024*1024);
    const int x = tid & 31, y = tid >> 5;   // 32 x 8
    const int bx = (blockIdx.x & 31) * 32, by = (blockIdx.x >> 5) * 32;
#pragma unroll
    for (int j=0;j<4;++j)
      tile[y*4+j][x] = f2bf(src[(size_t)(by + y*4+j)*1024 + bx + x]);
    __syncthreads();
#pragma unroll
    for (int j=0;j<4;++j)
      dst[(size_t)(bx + y*4+j)*1024 + by + x] = tile[x][y*4+j];
  }
}

// ---------------- GEMM core: C[128 x BN] tile = (A @ Bt^T + bias) * oscale -----------
// BK=64, XOR-chunk-swizzled LDS (64-elem rows; chunk c of row r at slot c^(r&7)).
// Double-buffered, single barrier per K-step: prefetch kt+1 issued before compute kt.
template<int BN, bool OUT_F32, bool BIAS_ROW>
__device__ __forceinline__ void gemm_core(
    u16b* __restrict__ As, u16b* __restrict__ Bs,   // As[2][128*64], Bs[2][BN*64]
    const u16b* __restrict__ A, const u16b* __restrict__ Bt,
    const float* __restrict__ bias, void* __restrict__ Cv,
    int N, int K, int bm, int bn, float oscale) {
  constexpr int NT = BN / 32;                  // n-tiles per wave
  constexpr int ASTRIDE = 128*64;
  constexpr int BSTRIDE = BN*64;
  const int tid = threadIdx.x;
  const int lane = tid & 63, wave = tid >> 6;
  const int wm = wave >> 1, wn = wave & 1;
  const int l15 = lane & 15, l4 = lane >> 4;
  float4v acc[4][NT];
#pragma unroll
  for (int i=0;i<4;++i)
#pragma unroll
    for (int j=0;j<NT;++j) acc[i][j] = (float4v){0.f,0.f,0.f,0.f};

  auto stage = [&](int buf, int k0) {
#pragma unroll
    for (int j=0;j<4;++j) {                    // As: 128 rows x 8 chunks
      int idx = j*256 + tid;
      int row = idx >> 3, seg = idx & 7;
      int segg = seg ^ (row & 7);
      gl_lds16(&A[(size_t)(bm+row)*K + k0 + segg*8], &As[buf*ASTRIDE + idx*8]);
    }
#pragma unroll
    for (int j=0;j<BN/32;++j) {                // Bs: BN rows x 8 chunks
      int idx = j*256 + tid;
      int row = idx >> 3, seg = idx & 7;
      int segg = seg ^ (row & 7);
      gl_lds16(&Bt[(size_t)(bn+row)*K + k0 + segg*8], &Bs[buf*BSTRIDE + idx*8]);
    }
  };

  const int NK = K >> 6;
  stage(0, 0);
  __syncthreads();                             // drain: buf0 ready
  for (int kt = 0; kt < NK; ++kt) {
    const int cur = kt & 1;
    if (kt + 1 < NK) stage(cur ^ 1, (kt + 1) << 6);   // issue next tile's loads
    const u16b* Asb = As + cur*ASTRIDE;
    const u16b* Bsb = Bs + cur*BSTRIDE;
#pragma unroll
    for (int ks=0; ks<2; ++ks) {
      short8v af[4], bf[NT];
      const int cs = ((ks*4 + l4) ^ (l15 & 7)) * 8;
#pragma unroll
      for (int mt=0;mt<4;++mt)
        af[mt] = *(const short8v*)&Asb[(wm*64+mt*16+l15)*64 + cs];
#pragma unroll
      for (int nt=0;nt<NT;++nt)
        bf[nt] = *(const short8v*)&Bsb[(wn*(BN/2)+nt*16+l15)*64 + cs];
#pragma unroll
      for (int mt=0;mt<4;++mt)
#pragma unroll
        for (int nt=0;nt<NT;++nt)
          acc[mt][nt] = __builtin_amdgcn_mfma_f32_16x16x32_bf16(af[mt], bf[nt], acc[mt][nt], 0, 0, 0);
    }
    __syncthreads();   // drains this wave's prefetch (vmcnt 0) + all LDS reads:
                       // next buf ready, buf cur free for reuse. One barrier/K-step.
  }

#pragma unroll
  for (int nt=0;nt<NT;++nt) {
    int col = bn + wn*(BN/2) + nt*16 + l15;
    float bbc = BIAS_ROW ? 0.f : bias[col];
#pragma unroll
    for (int mt=0;mt<4;++mt) {
      int row0 = bm + wm*64 + mt*16 + l4*4;
#pragma unroll
      for (int r=0;r<4;++r) {
        float bb = BIAS_ROW ? bias[row0+r] : bbc;
        float v = (acc[mt][nt][r] + bb) * oscale;  // C/D: col=l15, row=l4*4+r
        if (OUT_F32) ((float*)Cv)[(size_t)(row0+r)*N + col] = v;
        else         ((u16b*)Cv)[(size_t)(row0+r)*N + col] = f2bf(v);
      }
    }
  }
}

// Q,K,V projections, flat grid 768, XCD-swizzled.
__global__ __launch_bounds__(256) void gemm_qkv(
    const u16b* __restrict__ x1b, const u16b* __restrict__ x2b,
    const u16b* __restrict__ WT, const float* __restrict__ bq,
    const float* __restrict__ bk, const float* __restrict__ bv,
    u16b* __restrict__ QKV) {
  __shared__ __align__(16) u16b As[2*128*64];
  __shared__ __align__(16) u16b Bs[2*128*64];
  const int f = blockIdx.x;
  const int xcd = f & 7, s = f >> 3;
  const int z = s >> 5, t = s & 31;
  const size_t Mi = 1024*1024;
  const float QSCALE = 0.125f * 1.4426950408889634f;   // 1/sqrt(Dh) * log2(e)
  if (z == 2) {
    int bm = (t & 7) * 128;                  // WvT rows (d)
    int bn = (xcd*4 + (t >> 3)) * 128;       // tokens
    gemm_core<128,false,true>(As, Bs, WT + 2*Mi, x2b, bv, QKV + 8*Mi,
                              4096, 1024, bm, bn, 1.0f);
  } else {
    int bm = (xcd*4 + (t >> 3)) * 128;       // tokens
    int bn = (t & 7) * 128;                  // d_model cols
    gemm_core<128,false,false>(As, Bs, z ? x2b : x1b, WT + (size_t)z*Mi,
                               z ? bk : bq, QKV + (size_t)z*4*Mi,
                               1024, 1024, bm, bn, z ? 1.0f : QSCALE);
  }
}

// final projection, fp32 out; flat grid 512, XCD-swizzled
__global__ __launch_bounds__(256) void gemm_out(
    const u16b* __restrict__ A, const u16b* __restrict__ Bt,
    const float* __restrict__ bias, float* __restrict__ C) {
  __shared__ __align__(16) u16b As[2*128*64];
  __shared__ __align__(16) u16b Bs[2*64*64];
  const int f = blockIdx.x;
  const int xcd = f & 7, s = f >> 3;
  const int bm = (xcd*4 + (s >> 4)) * 128;
  const int bn = (s & 15) * 64;
  gemm_core<64,true,false>(As, Bs, A, Bt, bias, C, 1024, 1024, bm, bn, 1.0f);
}

// ---------------- flash attention: 128 q x 128 kv, VGPR-prefetch pipeline ------------
// grid (32 bh, 16 qtile): XCD = bh%8. Static-max base-2 softmax; P truncated bf16;
// l = P @ ones via MFMA. Tile kt+1 loaded global->VGPR after barrier B of iter kt
// (one full compute phase of latency cover), ds_written to the single LDS buffer at
// iter kt+1. All waits compiler-managed; no memory ops in flight across barriers.
// LDS: Ks 16K + Vs 16K + Ps 16K = 49152 B -> 2 blocks/CU.
__device__ __forceinline__ void attn_load(
    const u16b* __restrict__ Kgb, const u16b* __restrict__ Vtb,
    int kvoff, int tid, short8v kreg[4], short8v vreg[4]) {
#pragma unroll
  for (int j=0; j<4; ++j) {
    int idx = j*256 + tid;
    int rowk = idx >> 3, segk = idx & 7;
    kreg[j] = *(const short8v*)&Kgb[(size_t)(kvoff+rowk)*1024 + ((segk ^ (rowk & 7))*8)];
    int rowv = idx >> 4, segv = idx & 15;
    vreg[j] = *(const short8v*)&Vtb[(size_t)rowv*4096 + kvoff + ((segv ^ (rowv & 15))*8)];
  }
}

__global__ __launch_bounds__(256, 2) void attn_q128(
    const u16b* __restrict__ Q, const u16b* __restrict__ Kg,
    const u16b* __restrict__ Vt, u16b* __restrict__ O) {
  __shared__ __align__(16) u16b Ks[128*64];    // [kv][d]   chunk-swizzled
  __shared__ __align__(16) u16b Vs[64*128];    // [d][kv]   chunk-swizzled
  __shared__ __align__(16) u16b Ps[4*2*1024];  // per-wave per-group P [16q][64kv] swz
  const int tid = threadIdx.x;
  const int lane = tid & 63, wave = tid >> 6;
  const int l15 = lane & 15, l4 = lane >> 4;
  const int bh = blockIdx.x;
  const int b = bh >> 4, h = bh & 15;
  const int q0 = blockIdx.y * 128;
  const size_t seqbase = (size_t)b * 2048;
  const int colh = h * 64;
  const u16b* Kgb = Kg + seqbase*1024 + colh;
  const u16b* Vtb = Vt + (size_t)(h*64)*4096 + (size_t)b*2048;
  u16b* Pw = Ps + wave * 2048;

  // prefetch tile 0 into registers
  short8v kreg[4], vreg[4];
  attn_load(Kgb, Vtb, 0, tid, kreg, vreg);

  short8v qf[2][2];                            // [group][ks] — Q pre-scaled by GEMM
#pragma unroll
  for (int g=0; g<2; ++g) {
    size_t qrow = seqbase + q0 + wave*32 + g*16 + l15;
#pragma unroll
    for (int ks=0; ks<2; ++ks)
      qf[g][ks] = *(const short8v*)&Q[qrow*1024 + colh + ks*32 + l4*8];
  }

  short8v ones;                                 // bf16 1.0 B-fragment
#pragma unroll
  for (int i=0;i<8;++i) ones[i] = (short)0x3F80;

  float4v lacc[2] = {(float4v){0.f,0.f,0.f,0.f}, (float4v){0.f,0.f,0.f,0.f}};
  float4v oacc[2][4];
#pragma unroll
  for (int g=0; g<2; ++g)
#pragma unroll
    for (int nb=0; nb<4; ++nb) oacc[g][nb] = (float4v){0.f,0.f,0.f,0.f};

  for (int kt = 0; kt < 16; ++kt) {
    // barrier A: all waves done reading Ks/Vs (iter kt-1)
    __syncthreads();
    // stage tile kt from registers (compiler waits the prefetch loads here —
    // they've had a full compute phase to land)
#pragma unroll
    for (int j=0; j<4; ++j) {
      int idx = j*256 + tid;
      *(short8v*)&Ks[idx*8] = kreg[j];
      *(short8v*)&Vs[idx*8] = vreg[j];
    }
    // barrier B: writes visible block-wide
    __syncthreads();
    // prefetch tile kt+1 (in flight during compute kt; consumed at iter kt+1)
    if (kt < 15)
      attn_load(Kgb, Vtb, (kt+1)*128, tid, kreg, vreg);

    // S^T = K·Q^T: C/D col=q=l15, row=kv=nb*16+l4*4+r; kf shared across groups
    float4v sacc[2][8];
#pragma unroll
    for (int g=0; g<2; ++g)
#pragma unroll
      for (int nb=0; nb<8; ++nb) sacc[g][nb] = (float4v){0.f,0.f,0.f,0.f};
#pragma unroll
    for (int nb=0; nb<8; ++nb)
#pragma unroll
      for (int ks=0; ks<2; ++ks) {
        short8v kf = *(const short8v*)&Ks[(nb*16+l15)*64 + (((ks*4+l4) ^ (l15 & 7))*8)];
        sacc[0][nb] = __builtin_amdgcn_mfma_f32_16x16x32_bf16(kf, qf[0][ks], sacc[0][nb], 0, 0, 0);
        sacc[1][nb] = __builtin_amdgcn_mfma_f32_16x16x32_bf16(kf, qf[1][ks], sacc[1][nb], 0, 0, 0);
      }

    // two 64-kv halves: exp2 -> truncated P -> wave-local fence -> PV (+ l via MFMA)
#pragma unroll
    for (int h2=0; h2<2; ++h2) {
#pragma unroll
      for (int g=0; g<2; ++g)
#pragma unroll
        for (int nbl=0; nbl<4; ++nbl) {
          const float4v s4 = sacc[g][h2*4 + nbl];
          unsigned int u0 = __float_as_uint(exp2_fast(s4[0]));
          unsigned int u1 = __float_as_uint(exp2_fast(s4[1]));
          unsigned int u2 = __float_as_uint(exp2_fast(s4[2]));
          unsigned int u3 = __float_as_uint(exp2_fast(s4[3]));
          uint2v dw;
          dw[0] = (u0 >> 16) | (u1 & 0xFFFF0000u);
          dw[1] = (u2 >> 16) | (u3 & 0xFFFF0000u);
          *(uint2v*)&Pw[g*1024 + l15*64 + (((nbl*4 + l4) ^ l15)*4)] = dw;
        }
      asm volatile("s_waitcnt lgkmcnt(0)" ::: "memory");

#pragma unroll
      for (int ks2=0; ks2<2; ++ks2) {
        short8v pf[2];
#pragma unroll
        for (int g=0; g<2; ++g) {
          int c0 = (ks2*8 + l4*2) ^ l15;
          int c1 = (ks2*8 + l4*2 + 1) ^ l15;
          short4v pa = *(const short4v*)&Pw[g*1024 + l15*64 + c0*4];
          short4v pb = *(const short4v*)&Pw[g*1024 + l15*64 + c1*4];
          short8v p;
          p[0]=pa[0]; p[1]=pa[1]; p[2]=pa[2]; p[3]=pa[3];
          p[4]=pb[0]; p[5]=pb[1]; p[6]=pb[2]; p[7]=pb[3];
          pf[g] = p;
          lacc[g] = __builtin_amdgcn_mfma_f32_16x16x32_bf16(p, ones, lacc[g], 0, 0, 0);
        }
#pragma unroll
        for (int nb=0; nb<4; ++nb) {
          int cc = (h2*8 + ks2*4 + l4) ^ l15;
          short8v vf = *(const short8v*)&Vs[(nb*16+l15)*128 + cc*8];
          oacc[0][nb] = __builtin_amdgcn_mfma_f32_16x16x32_bf16(pf[0], vf, oacc[0][nb], 0, 0, 0);
          oacc[1][nb] = __builtin_amdgcn_mfma_f32_16x16x32_bf16(pf[1], vf, oacc[1][nb], 0, 0, 0);
        }
      }
    }
  }

  // epilogue: lacc[g][r] is l for this group's q=l4*4+r (replicated over l15)
#pragma unroll
  for (int g=0; g<2; ++g)
#pragma unroll
    for (int r=0; r<4; ++r) {
      float inv = 1.0f / lacc[g][r];
      size_t row = seqbase + q0 + wave*32 + g*16 + l4*4 + r;
#pragma unroll
      for (int nb=0; nb<4; ++nb)
        O[row*1024 + colh + nb*16 + l15] = f2bf(oacc[g][nb][r] * inv);
    }
}

extern "C" void kernel_launch(void* const* d_in, const int* in_sizes, int n_in,
                              void* d_out, int out_size, void* d_ws, size_t ws_size,
                              hipStream_t stream) {
  const float* x1 = (const float*)d_in[0];
  const float* x2 = (const float*)d_in[1];
  const float* Wq = (const float*)d_in[2];
  const float* bq = (const float*)d_in[3];
  const float* Wk = (const float*)d_in[4];
  const float* bk = (const float*)d_in[5];
  const float* Wv = (const float*)d_in[6];
  const float* bv = (const float*)d_in[7];
  const float* Wo = (const float*)d_in[8];
  const float* bo = (const float*)d_in[9];
  (void)in_sizes; (void)n_in; (void)out_size; (void)ws_size;

  u16b* ws = (u16b*)d_ws;
  const size_t Mi = 1024*1024;
  u16b* WT  = ws;               // WqT,WkT,WvT contiguous + WoT
  u16b* WoT = ws + 3*Mi;
  u16b* x1b = ws + 4*Mi;        // Cx aliases after Q-gemm consumed it
  u16b* x2b = ws + 8*Mi;
  u16b* QKV = ws + 12*Mi;       // Qb, Kb, Vtb (4Mi each) -> 48 MiB total
  u16b* Qb  = QKV;
  u16b* Kb  = QKV + 4*Mi;
  u16b* Vtb = QKV + 8*Mi;       // Vt[h*64+d][b*2048+kv], stride 4096
  u16b* Cx  = x1b;

  prep<<<dim3(1024,6), 256, 0, stream>>>(x1, x2, Wq, Wk, Wv, Wo, x1b, x2b, WT);

  gemm_qkv<<<dim3(768), 256, 0, stream>>>(x1b, x2b, WT, bq, bk, bv, QKV);

  attn_q128<<<dim3(32,16), 256, 0, stream>>>(Qb, Kb, Vtb, Cx);

  gemm_out<<<dim3(512), 256, 0, stream>>>(Cx, WoT, bo, (float*)d_out);
}

// Round 3
// 200.636 us; speedup vs baseline: 1.0914x; 1.0914x over previous
//
#include <hip/hip_runtime.h>
#include <stdint.h>

// MultiHeadCrossAttention: B=2, SQ=SK=2048, D=1024, H=16, Dh=64, scale=1/8.
// fp32 in/out, bf16 MFMA internal.
// R13: identical to R12 (bench infra failed twice on R12 — no measurement, node was
//      degraded in R1 already: 472s npz push). Hazard re-audit found no race/deadlock:
//      uniform control flow (barrier counts match), every LDS overwrite >=2 barriers
//      after its last reader's lgkmcnt(0), vmcnt(4) FIFO induction verified for
//      prologue/steady/tail. Resubmitting unchanged for clean attribution.
// R12: gemm_qkv moved from 128^2 2-phase dbuf (measured at its 655-TF-class
//      structural ceiling: Mfma 18.5%, all pipes idle -> latency-bound at the
//      end-of-tile vmcnt(0) drain) to the 256^2 8-phase counted-vmcnt schedule
//      (m201/m248 template): 4 quadrant-phases per K-tile, stages 2 half-tiles
//      ahead, vmcnt(4) once per K-tile (never 0 in steady state), raw s_barrier
//      + explicit lgkmcnt + sched_barrier fences, setprio(1) around MFMA.
//      gemm_out/attn/prep unchanged from R11.

typedef unsigned short u16b;
typedef __attribute__((ext_vector_type(4))) short short4v;
typedef __attribute__((ext_vector_type(8))) short short8v;
typedef __attribute__((ext_vector_type(4))) float float4v;
typedef __attribute__((ext_vector_type(2))) unsigned int uint2v;

#if __has_builtin(__builtin_amdgcn_exp2f)
__device__ __forceinline__ float exp2_fast(float x){ return __builtin_amdgcn_exp2f(x); }
#else
__device__ __forceinline__ float exp2_fast(float x){ return exp2f(x); }
#endif

__device__ __forceinline__ u16b f2bf(float f) {
  union { float f; unsigned int i; } v; v.f = f;
  return (u16b)((v.i + 0x7fffu + ((v.i >> 16) & 1u)) >> 16);  // RNE
}
__device__ __forceinline__ void gl_lds16(const u16b* g, u16b* l) {
  __builtin_amdgcn_global_load_lds(
      (const __attribute__((address_space(1))) void*)g,
      (__attribute__((address_space(3))) void*)l, 16, 0, 0);
}

#define FENCE_BARRIER() do { asm volatile("" ::: "memory"); \
  __builtin_amdgcn_s_barrier(); asm volatile("" ::: "memory"); } while(0)
#define LGKM0() do { asm volatile("s_waitcnt lgkmcnt(0)" ::: "memory"); \
  __builtin_amdgcn_sched_barrier(0); } while(0)
#define VMCNT(n) do { asm volatile("s_waitcnt vmcnt(" #n ")" ::: "memory"); \
  __builtin_amdgcn_sched_barrier(0); } while(0)

// ---------------- prep: y=0,1 -> cvt x1/x2 fp32->bf16 ; y=2..5 -> transpose W[y-2] ---
__global__ __launch_bounds__(256) void prep(
    const float* __restrict__ x1, const float* __restrict__ x2,
    const float* __restrict__ W0, const float* __restrict__ W1,
    const float* __restrict__ W2, const float* __restrict__ W3,
    u16b* __restrict__ x1b, u16b* __restrict__ x2b, u16b* __restrict__ WT) {
  const int tid = threadIdx.x;
  const int mode = blockIdx.y;
  if (mode < 2) {
    const float* src = mode ? x2 : x1;
    u16b* dst = mode ? x2b : x1b;
    const int n4 = 1024*1024;             // 4Mi elems / 4
    int i = blockIdx.x * 256 + tid;
    const int stride = gridDim.x * 256;
    for (; i < n4; i += stride) {
      float4v v = ((const float4v*)src)[i];
      short4v o;
      o[0]=(short)f2bf(v[0]); o[1]=(short)f2bf(v[1]);
      o[2]=(short)f2bf(v[2]); o[3]=(short)f2bf(v[3]);
      ((short4v*)dst)[i] = o;
    }
  } else {
    __shared__ u16b tile[32][33];
    const int z = mode - 2;
    const float* src = (z==0) ? W0 : (z==1) ? W1 : (z==2) ? W2 : W3;
    u16b* dst = WT + (size_t)z * (1024*1024);
    const int x = tid & 31, y = tid >> 5;   // 32 x 8
    const int bx = (blockIdx.x & 31) * 32, by = (blockIdx.x >> 5) * 32;
#pragma unroll
    for (int j=0;j<4;++j)
      tile[y*4+j][x] = f2bf(src[(size_t)(by + y*4+j)*1024 + bx + x]);
    __syncthreads();
#pragma unroll
    for (int j=0;j<4;++j)
      dst[(size_t)(bx + y*4+j)*1024 + by + x] = tile[x][y*4+j];
  }
}

// ---------------- 256x256 8-phase GEMM core -----------------------------------------
// C[256 x 256] = (A @ Bt^T + bias) * oscale. BK=64, K=1024 (NK=16 tiles).
// LDS: As[2][256*64] + Bs[2][256*64] = 128 KiB. 512 threads = 8 waves, arranged
// 2x4 inside each 128x128 C-quadrant (per-wave 64x32 patch per quadrant).
// Phase/quadrant order: (0,0),(0,1),(1,0),(1,1).
//   A-half0 last read ph2, A-half1 ph3(regs reused ph4), B-half0 LDS-read ph1
//   (cached in regs for ph3), B-half1 LDS-read ph2 (cached for ph4).
// Stage schedule per tile t:  ph1 -> (t+1):A1 [next buf, dead since t-1 ended]
//   ph2 -> (t+1):B1 [next buf]   ph3 -> (t+2):A0 [cur buf; A0 dead after ph2]
//   ph4 -> (t+2):B0 [cur buf; B0 dead after ph1's lgkmcnt0 + barrier]
// vmcnt(4) at ph4 (FIFO retire): guarantees ALL of tile t+1 landed, leaves
// (t+2):A0,B0 (4 loads) in flight. Tail: vmcnt(0) at t==NK-2.
template<bool BIAS_ROW>
__device__ __forceinline__ void gemm256_core(
    u16b* __restrict__ As, u16b* __restrict__ Bs,
    const u16b* __restrict__ A, const u16b* __restrict__ Bt,
    const float* __restrict__ bias, u16b* __restrict__ C,
    int N, int K, int bm, int bn, float oscale) {
  constexpr int ASTR = 256*64, BSTR = 256*64;
  const int tid = threadIdx.x;
  const int lane = tid & 63, wave = tid >> 6;
  const int wr = wave >> 2, wc = wave & 3;      // 2x4 waves in a quadrant
  const int l15 = lane & 15, l4 = lane >> 4;

  auto stage_half = [&](const u16b* __restrict__ G, int row0, int k0,
                        u16b* __restrict__ Lbase) {
#pragma unroll
    for (int j=0;j<2;++j) {                     // 128 rows x 8 chunks, 2 loads/thr
      int idx = j*512 + tid;
      int row = idx >> 3, seg = idx & 7;
      int segg = seg ^ (row & 7);
      gl_lds16(&G[(size_t)(row0+row)*K + k0 + segg*8], &Lbase[idx*8]);
    }
  };

  float4v acc[2][2][4][2];
#pragma unroll
  for (int qm=0;qm<2;++qm)
#pragma unroll
  for (int qn=0;qn<2;++qn)
#pragma unroll
  for (int m=0;m<4;++m)
#pragma unroll
  for (int n=0;n<2;++n) acc[qm][qn][m][n] = (float4v){0.f,0.f,0.f,0.f};

  const int NK = K >> 6;
  // ---- prologue: tile0 all 4 halves + tile1 A0,B0 (12 loads/thr) --------------
  stage_half(A,  bm+0,   0,  As + 0);           // t0:A0
  stage_half(Bt, bn+0,   0,  Bs + 0);           // t0:B0
  stage_half(A,  bm+128, 0,  As + 128*64);      // t0:A1
  stage_half(Bt, bn+128, 0,  Bs + 128*64);      // t0:B1
  stage_half(A,  bm+0,   64, As + ASTR);        // t1:A0
  stage_half(Bt, bn+0,   64, Bs + BSTR);        // t1:B0
  VMCNT(4);                                     // t0 fully landed; t1:A0,B0 in flight
  FENCE_BARRIER();

  int cur = 0;
  for (int t = 0; t < NK; ++t) {
    u16b* Ac = As + cur*ASTR;  u16b* Bc = Bs + cur*BSTR;
    u16b* An = As + (cur^1)*ASTR;  u16b* Bn = Bs + (cur^1)*BSTR;
    const int k1 = (t+1) << 6, k2 = (t+2) << 6;
    short8v af[4][2], bf0[2][2], bf1[2][2];

    // ---- ph1: quad (0,0). reads A0 + B0; stage (t+1):A1 -> next buf ----------
#pragma unroll
    for (int m=0;m<4;++m)
#pragma unroll
      for (int ks=0;ks<2;++ks)
        af[m][ks] = *(const short8v*)&Ac[(0*128 + wr*64 + m*16 + l15)*64
                                         + (((ks*4+l4) ^ (l15&7))*8)];
#pragma unroll
    for (int n=0;n<2;++n)
#pragma unroll
      for (int ks=0;ks<2;++ks)
        bf0[n][ks] = *(const short8v*)&Bc[(0*128 + wc*32 + n*16 + l15)*64
                                          + (((ks*4+l4) ^ (l15&7))*8)];
    if (t+1 < NK) stage_half(A, bm+128, k1, An + 128*64);
    FENCE_BARRIER();
    LGKM0();
    __builtin_amdgcn_s_setprio(1);
#pragma unroll
    for (int m=0;m<4;++m)
#pragma unroll
      for (int n=0;n<2;++n)
#pragma unroll
        for (int ks=0;ks<2;++ks)
          acc[0][0][m][n] = __builtin_amdgcn_mfma_f32_16x16x32_bf16(
              af[m][ks], bf0[n][ks], acc[0][0][m][n], 0, 0, 0);
    __builtin_amdgcn_s_setprio(0);
    FENCE_BARRIER();

    // ---- ph2: quad (0,1). reads B1 (af reused); stage (t+1):B1 -> next buf ---
#pragma unroll
    for (int n=0;n<2;++n)
#pragma unroll
      for (int ks=0;ks<2;++ks)
        bf1[n][ks] = *(const short8v*)&Bc[(1*128 + wc*32 + n*16 + l15)*64
                                          + (((ks*4+l4) ^ (l15&7))*8)];
    if (t+1 < NK) stage_half(Bt, bn+128, k1, Bn + 128*64);
    FENCE_BARRIER();
    LGKM0();
    __builtin_amdgcn_s_setprio(1);
#pragma unroll
    for (int m=0;m<4;++m)
#pragma unroll
      for (int n=0;n<2;++n)
#pragma unroll
        for (int ks=0;ks<2;++ks)
          acc[0][1][m][n] = __builtin_amdgcn_mfma_f32_16x16x32_bf16(
              af[m][ks], bf1[n][ks], acc[0][1][m][n], 0, 0, 0);
    __builtin_amdgcn_s_setprio(0);
    FENCE_BARRIER();

    // ---- ph3: quad (1,0). reads A1 (bf0 from regs); stage (t+2):A0 -> cur.A0 -
    // cur.A0 readers (ph1/ph2 af) drained at ph1's LGKM0, two barriers ago: safe.
#pragma unroll
    for (int m=0;m<4;++m)
#pragma unroll
      for (int ks=0;ks<2;++ks)
        af[m][ks] = *(const short8v*)&Ac[(1*128 + wr*64 + m*16 + l15)*64
                                         + (((ks*4+l4) ^ (l15&7))*8)];
    if (t+2 < NK) stage_half(A, bm+0, k2, Ac + 0);
    FENCE_BARRIER();
    LGKM0();
    __builtin_amdgcn_s_setprio(1);
#pragma unroll
    for (int m=0;m<4;++m)
#pragma unroll
      for (int n=0;n<2;++n)
#pragma unroll
        for (int ks=0;ks<2;++ks)
          acc[1][0][m][n] = __builtin_amdgcn_mfma_f32_16x16x32_bf16(
              af[m][ks], bf0[n][ks], acc[1][0][m][n], 0, 0, 0);
    __builtin_amdgcn_s_setprio(0);
    FENCE_BARRIER();

    // ---- ph4: quad (1,1). all operands in regs; stage (t+2):B0 -> cur.B0 -----
    // cur.B0 last LDS-read at ph1 (cached since): safe.
    if (t+2 < NK) stage_half(Bt, bn+0, k2, Bc + 0);
    FENCE_BARRIER();
    LGKM0();
    __builtin_amdgcn_s_setprio(1);
#pragma unroll
    for (int m=0;m<4;++m)
#pragma unroll
      for (int n=0;n<2;++n)
#pragma unroll
        for (int ks=0;ks<2;++ks)
          acc[1][1][m][n] = __builtin_amdgcn_mfma_f32_16x16x32_bf16(
              af[m][ks], bf1[n][ks], acc[1][1][m][n], 0, 0, 0);
    __builtin_amdgcn_s_setprio(0);
    if (t == NK-2) { VMCNT(0); }                 // tail: next tile has nothing newer
    else          { VMCNT(4); }                  // tile t+1 fully landed; 2 halves fly
    FENCE_BARRIER();
    cur ^= 1;
  }

  // ---- epilogue ---------------------------------------------------------------
#pragma unroll
  for (int qm=0;qm<2;++qm)
#pragma unroll
  for (int qn=0;qn<2;++qn)
#pragma unroll
  for (int n=0;n<2;++n) {
    int col = bn + qn*128 + wc*32 + n*16 + l15;
    float bbc = BIAS_ROW ? 0.f : bias[col];
#pragma unroll
    for (int m=0;m<4;++m) {
      int row0 = bm + qm*128 + wr*64 + m*16 + l4*4;
#pragma unroll
      for (int r=0;r<4;++r) {
        float bb = BIAS_ROW ? bias[row0+r] : bbc;
        float v = (acc[qm][qn][m][n][r] + bb) * oscale;
        C[(size_t)(row0+r)*N + col] = f2bf(v);
      }
    }
  }
}

// Q / K / V^T projections, 192 blocks x 512 threads, per-z XCD-chunked swizzle.
__global__ __launch_bounds__(512, 2) void gemm_qkv256(
    const u16b* __restrict__ x1b, const u16b* __restrict__ x2b,
    const u16b* __restrict__ WT, const float* __restrict__ bq,
    const float* __restrict__ bk, const float* __restrict__ bv,
    u16b* __restrict__ QKV) {
  __shared__ __align__(16) u16b As[2*256*64];
  __shared__ __align__(16) u16b Bs[2*256*64];
  const int f = blockIdx.x;
  const int z = f >> 6;                      // 0=Q, 1=K, 2=V^T
  const int u = f & 63;
  const int w = ((u & 7) << 3) | (u >> 3);   // xcd = u&7 gets 8 contiguous tiles
  const size_t Mi = 1024*1024;
  const float QSCALE = 0.125f * 1.4426950408889634f;   // 1/sqrt(Dh) * log2(e)
  if (z == 2) {
    int bm = (w >> 4) * 256;                 // WvT rows (d)
    int bn = (w & 15) * 256;                 // tokens
    gemm256_core<true>(As, Bs, WT + 2*Mi, x2b, bv, QKV + 8*Mi,
                       4096, 1024, bm, bn, 1.0f);
  } else {
    int bm = (w >> 2) * 256;                 // tokens
    int bn = (w & 3) * 256;                  // d_model cols
    gemm256_core<false>(As, Bs, z ? x2b : x1b, WT + (size_t)z*Mi,
                        z ? bk : bq, QKV + (size_t)z*4*Mi,
                        1024, 1024, bm, bn, z ? 1.0f : QSCALE);
  }
}

// ---------------- 128-tile GEMM core (gemm_out): 2-phase dbuf pipeline --------------
template<int BN, bool OUT_F32, bool BIAS_ROW>
__device__ __forceinline__ void gemm_core(
    u16b* __restrict__ As, u16b* __restrict__ Bs,   // As[2][128*64], Bs[2][BN*64]
    const u16b* __restrict__ A, const u16b* __restrict__ Bt,
    const float* __restrict__ bias, void* __restrict__ Cv,
    int N, int K, int bm, int bn, float oscale) {
  constexpr int NT = BN / 32;                  // n-tiles per wave
  constexpr int ASTRIDE = 128*64;
  constexpr int BSTRIDE = BN*64;
  const int tid = threadIdx.x;
  const int lane = tid & 63, wave = tid >> 6;
  const int wm = wave >> 1, wn = wave & 1;
  const int l15 = lane & 15, l4 = lane >> 4;
  float4v acc[4][NT];
#pragma unroll
  for (int i=0;i<4;++i)
#pragma unroll
    for (int j=0;j<NT;++j) acc[i][j] = (float4v){0.f,0.f,0.f,0.f};

  auto stage = [&](int buf, int k0) {
#pragma unroll
    for (int j=0;j<4;++j) {                    // As: 128 rows x 8 chunks
      int idx = j*256 + tid;
      int row = idx >> 3, seg = idx & 7;
      int segg = seg ^ (row & 7);
      gl_lds16(&A[(size_t)(bm+row)*K + k0 + segg*8], &As[buf*ASTRIDE + idx*8]);
    }
#pragma unroll
    for (int j=0;j<BN/32;++j) {                // Bs: BN rows x 8 chunks
      int idx = j*256 + tid;
      int row = idx >> 3, seg = idx & 7;
      int segg = seg ^ (row & 7);
      gl_lds16(&Bt[(size_t)(bn+row)*K + k0 + segg*8], &Bs[buf*BSTRIDE + idx*8]);
    }
  };

  const int NK = K >> 6;
  stage(0, 0);
  __syncthreads();                             // drain: buf0 ready
  for (int kt = 0; kt < NK; ++kt) {
    const int cur = kt & 1;
    if (kt + 1 < NK) stage(cur ^ 1, (kt + 1) << 6);   // issue next tile's loads
    const u16b* Asb = As + cur*ASTRIDE;
    const u16b* Bsb = Bs + cur*BSTRIDE;
#pragma unroll
    for (int ks=0; ks<2; ++ks) {
      short8v af[4], bf[NT];
      const int cs = ((ks*4 + l4) ^ (l15 & 7)) * 8;
#pragma unroll
      for (int mt=0;mt<4;++mt)
        af[mt] = *(const short8v*)&Asb[(wm*64+mt*16+l15)*64 + cs];
#pragma unroll
      for (int nt=0;nt<NT;++nt)
        bf[nt] = *(const short8v*)&Bsb[(wn*(BN/2)+nt*16+l15)*64 + cs];
#pragma unroll
      for (int mt=0;mt<4;++mt)
#pragma unroll
        for (int nt=0;nt<NT;++nt)
          acc[mt][nt] = __builtin_amdgcn_mfma_f32_16x16x32_bf16(af[mt], bf[nt], acc[mt][nt], 0, 0, 0);
    }
    __syncthreads();   // drains this wave's prefetch (vmcnt 0) + all LDS reads
  }

#pragma unroll
  for (int nt=0;nt<NT;++nt) {
    int col = bn + wn*(BN/2) + nt*16 + l15;
    float bbc = BIAS_ROW ? 0.f : bias[col];
#pragma unroll
    for (int mt=0;mt<4;++mt) {
      int row0 = bm + wm*64 + mt*16 + l4*4;
#pragma unroll
      for (int r=0;r<4;++r) {
        float bb = BIAS_ROW ? bias[row0+r] : bbc;
        float v = (acc[mt][nt][r] + bb) * oscale;  // C/D: col=l15, row=l4*4+r
        if (OUT_F32) ((float*)Cv)[(size_t)(row0+r)*N + col] = v;
        else         ((u16b*)Cv)[(size_t)(row0+r)*N + col] = f2bf(v);
      }
    }
  }
}

// final projection, fp32 out; flat grid 512, XCD-swizzled
__global__ __launch_bounds__(256) void gemm_out(
    const u16b* __restrict__ A, const u16b* __restrict__ Bt,
    const float* __restrict__ bias, float* __restrict__ C) {
  __shared__ __align__(16) u16b As[2*128*64];
  __shared__ __align__(16) u16b Bs[2*64*64];
  const int f = blockIdx.x;
  const int xcd = f & 7, s = f >> 3;
  const int bm = (xcd*4 + (s >> 4)) * 128;
  const int bn = (s & 15) * 64;
  gemm_core<64,true,false>(As, Bs, A, Bt, bias, C, 1024, 1024, bm, bn, 1.0f);
}

// ---------------- flash attention: 128 q x 128 kv, VGPR-prefetch pipeline ------------
__device__ __forceinline__ void attn_load(
    const u16b* __restrict__ Kgb, const u16b* __restrict__ Vtb,
    int kvoff, int tid, short8v kreg[4], short8v vreg[4]) {
#pragma unroll
  for (int j=0; j<4; ++j) {
    int idx = j*256 + tid;
    int rowk = idx >> 3, segk = idx & 7;
    kreg[j] = *(const short8v*)&Kgb[(size_t)(kvoff+rowk)*1024 + ((segk ^ (rowk & 7))*8)];
    int rowv = idx >> 4, segv = idx & 15;
    vreg[j] = *(const short8v*)&Vtb[(size_t)rowv*4096 + kvoff + ((segv ^ (rowv & 15))*8)];
  }
}

__global__ __launch_bounds__(256, 2) void attn_q128(
    const u16b* __restrict__ Q, const u16b* __restrict__ Kg,
    const u16b* __restrict__ Vt, u16b* __restrict__ O) {
  __shared__ __align__(16) u16b Ks[128*64];    // [kv][d]   chunk-swizzled
  __shared__ __align__(16) u16b Vs[64*128];    // [d][kv]   chunk-swizzled
  __shared__ __align__(16) u16b Ps[4*2*1024];  // per-wave per-group P [16q][64kv] swz
  const int tid = threadIdx.x;
  const int lane = tid & 63, wave = tid >> 6;
  const int l15 = lane & 15, l4 = lane >> 4;
  const int bh = blockIdx.x;
  const int b = bh >> 4, h = bh & 15;
  const int q0 = blockIdx.y * 128;
  const size_t seqbase = (size_t)b * 2048;
  const int colh = h * 64;
  const u16b* Kgb = Kg + seqbase*1024 + colh;
  const u16b* Vtb = Vt + (size_t)(h*64)*4096 + (size_t)b*2048;
  u16b* Pw = Ps + wave * 2048;

  // prefetch tile 0 into registers
  short8v kreg[4], vreg[4];
  attn_load(Kgb, Vtb, 0, tid, kreg, vreg);

  short8v qf[2][2];                            // [group][ks] — Q pre-scaled by GEMM
#pragma unroll
  for (int g=0; g<2; ++g) {
    size_t qrow = seqbase + q0 + wave*32 + g*16 + l15;
#pragma unroll
    for (int ks=0; ks<2; ++ks)
      qf[g][ks] = *(const short8v*)&Q[qrow*1024 + colh + ks*32 + l4*8];
  }

  short8v ones;                                 // bf16 1.0 B-fragment
#pragma unroll
  for (int i=0;i<8;++i) ones[i] = (short)0x3F80;

  float4v lacc[2] = {(float4v){0.f,0.f,0.f,0.f}, (float4v){0.f,0.f,0.f,0.f}};
  float4v oacc[2][4];
#pragma unroll
  for (int g=0; g<2; ++g)
#pragma unroll
    for (int nb=0; nb<4; ++nb) oacc[g][nb] = (float4v){0.f,0.f,0.f,0.f};

  for (int kt = 0; kt < 16; ++kt) {
    // barrier A: all waves done reading Ks/Vs (iter kt-1)
    __syncthreads();
    // stage tile kt from registers
#pragma unroll
    for (int j=0; j<4; ++j) {
      int idx = j*256 + tid;
      *(short8v*)&Ks[idx*8] = kreg[j];
      *(short8v*)&Vs[idx*8] = vreg[j];
    }
    // barrier B: writes visible block-wide
    __syncthreads();
    // prefetch tile kt+1 (in flight during compute kt; consumed at iter kt+1)
    if (kt < 15)
      attn_load(Kgb, Vtb, (kt+1)*128, tid, kreg, vreg);

    // S^T = K·Q^T: C/D col=q=l15, row=kv=nb*16+l4*4+r; kf shared across groups
    float4v sacc[2][8];
#pragma unroll
    for (int g=0; g<2; ++g)
#pragma unroll
      for (int nb=0; nb<8; ++nb) sacc[g][nb] = (float4v){0.f,0.f,0.f,0.f};
#pragma unroll
    for (int nb=0; nb<8; ++nb)
#pragma unroll
      for (int ks=0; ks<2; ++ks) {
        short8v kf = *(const short8v*)&Ks[(nb*16+l15)*64 + (((ks*4+l4) ^ (l15 & 7))*8)];
        sacc[0][nb] = __builtin_amdgcn_mfma_f32_16x16x32_bf16(kf, qf[0][ks], sacc[0][nb], 0, 0, 0);
        sacc[1][nb] = __builtin_amdgcn_mfma_f32_16x16x32_bf16(kf, qf[1][ks], sacc[1][nb], 0, 0, 0);
      }

    // two 64-kv halves: exp2 -> truncated P -> wave-local fence -> PV (+ l via MFMA)
#pragma unroll
    for (int h2=0; h2<2; ++h2) {
#pragma unroll
      for (int g=0; g<2; ++g)
#pragma unroll
        for (int nbl=0; nbl<4; ++nbl) {
          const float4v s4 = sacc[g][h2*4 + nbl];
          unsigned int u0 = __float_as_uint(exp2_fast(s4[0]));
          unsigned int u1 = __float_as_uint(exp2_fast(s4[1]));
          unsigned int u2 = __float_as_uint(exp2_fast(s4[2]));
          unsigned int u3 = __float_as_uint(exp2_fast(s4[3]));
          uint2v dw;
          dw[0] = (u0 >> 16) | (u1 & 0xFFFF0000u);
          dw[1] = (u2 >> 16) | (u3 & 0xFFFF0000u);
          *(uint2v*)&Pw[g*1024 + l15*64 + (((nbl*4 + l4) ^ l15)*4)] = dw;
        }
      asm volatile("s_waitcnt lgkmcnt(0)" ::: "memory");

#pragma unroll
      for (int ks2=0; ks2<2; ++ks2) {
        short8v pf[2];
#pragma unroll
        for (int g=0; g<2; ++g) {
          int c0 = (ks2*8 + l4*2) ^ l15;
          int c1 = (ks2*8 + l4*2 + 1) ^ l15;
          short4v pa = *(const short4v*)&Pw[g*1024 + l15*64 + c0*4];
          short4v pb = *(const short4v*)&Pw[g*1024 + l15*64 + c1*4];
          short8v p;
          p[0]=pa[0]; p[1]=pa[1]; p[2]=pa[2]; p[3]=pa[3];
          p[4]=pb[0]; p[5]=pb[1]; p[6]=pb[2]; p[7]=pb[3];
          pf[g] = p;
          lacc[g] = __builtin_amdgcn_mfma_f32_16x16x32_bf16(p, ones, lacc[g], 0, 0, 0);
        }
#pragma unroll
        for (int nb=0; nb<4; ++nb) {
          int cc = (h2*8 + ks2*4 + l4) ^ l15;
          short8v vf = *(const short8v*)&Vs[(nb*16+l15)*128 + cc*8];
          oacc[0][nb] = __builtin_amdgcn_mfma_f32_16x16x32_bf16(pf[0], vf, oacc[0][nb], 0, 0, 0);
          oacc[1][nb] = __builtin_amdgcn_mfma_f32_16x16x32_bf16(pf[1], vf, oacc[1][nb], 0, 0, 0);
        }
      }
    }
  }

  // epilogue: lacc[g][r] is l for this group's q=l4*4+r (replicated over l15)
#pragma unroll
  for (int g=0; g<2; ++g)
#pragma unroll
    for (int r=0; r<4; ++r) {
      float inv = 1.0f / lacc[g][r];
      size_t row = seqbase + q0 + wave*32 + g*16 + l4*4 + r;
#pragma unroll
      for (int nb=0; nb<4; ++nb)
        O[row*1024 + colh + nb*16 + l15] = f2bf(oacc[g][nb][r] * inv);
    }
}

extern "C" void kernel_launch(void* const* d_in, const int* in_sizes, int n_in,
                              void* d_out, int out_size, void* d_ws, size_t ws_size,
                              hipStream_t stream) {
  const float* x1 = (const float*)d_in[0];
  const float* x2 = (const float*)d_in[1];
  const float* Wq = (const float*)d_in[2];
  const float* bq = (const float*)d_in[3];
  const float* Wk = (const float*)d_in[4];
  const float* bk = (const float*)d_in[5];
  const float* Wv = (const float*)d_in[6];
  const float* bv = (const float*)d_in[7];
  const float* Wo = (const float*)d_in[8];
  const float* bo = (const float*)d_in[9];
  (void)in_sizes; (void)n_in; (void)out_size; (void)ws_size;

  u16b* ws = (u16b*)d_ws;
  const size_t Mi = 1024*1024;
  u16b* WT  = ws;               // WqT,WkT,WvT contiguous + WoT
  u16b* WoT = ws + 3*Mi;
  u16b* x1b = ws + 4*Mi;        // Cx aliases after Q-gemm consumed it
  u16b* x2b = ws + 8*Mi;
  u16b* QKV = ws + 12*Mi;       // Qb, Kb, Vtb (4Mi each) -> 48 MiB total
  u16b* Qb  = QKV;
  u16b* Kb  = QKV + 4*Mi;
  u16b* Vtb = QKV + 8*Mi;       // Vt[h*64+d][b*2048+kv], stride 4096
  u16b* Cx  = x1b;

  prep<<<dim3(1024,6), 256, 0, stream>>>(x1, x2, Wq, Wk, Wv, Wo, x1b, x2b, WT);

  gemm_qkv256<<<dim3(192), 512, 0, stream>>>(x1b, x2b, WT, bq, bk, bv, QKV);

  attn_q128<<<dim3(32,16), 256, 0, stream>>>(Qb, Kb, Vtb, Cx);

  gemm_out<<<dim3(512), 256, 0, stream>>>(Cx, WoT, bo, (float*)d_out);
}